// Round 1
// baseline (269.404 us; speedup 1.0000x reference)
//
#include <hip/hip_runtime.h>
#include <hip/hip_bf16.h>
#include <cstdint>

typedef __bf16 bf16;
typedef bf16 bf16x8 __attribute__((ext_vector_type(8)));
typedef float f32x4 __attribute__((ext_vector_type(4)));

// Problem constants
#define NTOK 4096   // B*T
#define DLBL 512    // D_LABEL
#define NLAB 50

__device__ inline bf16x8 cvt8(float4 a, float4 b) {
  bf16x8 r;
  r[0] = (bf16)a.x; r[1] = (bf16)a.y; r[2] = (bf16)a.z; r[3] = (bf16)a.w;
  r[4] = (bf16)b.x; r[5] = (bf16)b.y; r[6] = (bf16)b.z; r[7] = (bf16)b.w;
  return r;
}

// ---------------------------------------------------------------------------
// Kernel 1: convert biaffine W [50][512][512] f32 -> bf16 (same layout)
// ---------------------------------------------------------------------------
__global__ __launch_bounds__(256) void convW_k(const float* __restrict__ W,
                                               bf16* __restrict__ Wb) {
  int i = blockIdx.x * 256 + threadIdx.x;          // 6400*256 threads, 8 elems each
  const float4* s = (const float4*)W + (size_t)i * 2;
  float4 a = s[0], b = s[1];
  *(bf16x8*)(Wb + (size_t)i * 8) = cvt8(a, b);
}

// ---------------------------------------------------------------------------
// Kernel 2: dep projection, TRANSPOSED output.
//   dep_t[e][tok] = sum_d dep_W[e][d] * dep[tok][d] + dep_b[e]
// A-operand = dep_W (rows e, k=d), B-operand = dep (cols tok, k=d). Natural.
// Tile: 128 e-rows x 64 tok-cols, BK=32, 4 waves (wr=w&1 row-half, wc=w>>1 col-half)
// ---------------------------------------------------------------------------
__global__ __launch_bounds__(256) void projA_k(const float* __restrict__ Wp,
                                               const float* __restrict__ X,
                                               const float* __restrict__ bv,
                                               bf16* __restrict__ outT) {
  __shared__ char lds[12288];
  char* ldsA = lds;          // [128 e][32 d] bf16
  char* ldsB = lds + 8192;   // [64 tok][32 d] bf16
  const int tid = threadIdx.x, l = tid & 63, w = tid >> 6;
  const int tokbase = blockIdx.x * 64;
  const int ebase   = blockIdx.y * 128;
  const int wr = w & 1, wc = w >> 1;
  f32x4 acc[4][2] = {};
  const int arow = tid >> 1, ahalf = tid & 1;      // A: 128 rows, 2 thr/row (32B each)
  const int brow = tid >> 2, bgr = tid & 3;        // B: 64 rows, 4 thr/row (16B each)
  const float* aS = Wp + (size_t)(ebase + arow) * 1024 + ahalf * 16;
  const float* bS = X  + (size_t)(tokbase + brow) * 1024 + bgr * 8;
  const int lo = (l & 15) * 64 + (l >> 4) * 16;
  for (int kb = 0; kb < 1024; kb += 32) {
    float4 a0 = *(const float4*)(aS + kb);
    float4 a1 = *(const float4*)(aS + kb + 4);
    float4 a2 = *(const float4*)(aS + kb + 8);
    float4 a3 = *(const float4*)(aS + kb + 12);
    float4 b0 = *(const float4*)(bS + kb);
    float4 b1 = *(const float4*)(bS + kb + 4);
    *(bf16x8*)(ldsA + arow * 64 + ahalf * 32)      = cvt8(a0, a1);
    *(bf16x8*)(ldsA + arow * 64 + ahalf * 32 + 16) = cvt8(a2, a3);
    *(bf16x8*)(ldsB + brow * 64 + bgr * 16)        = cvt8(b0, b1);
    __syncthreads();
    bf16x8 aF[4], bF[2];
#pragma unroll
    for (int i = 0; i < 4; ++i) aF[i] = *(bf16x8*)(ldsA + (wr * 64 + i * 16) * 64 + lo);
#pragma unroll
    for (int j = 0; j < 2; ++j) bF[j] = *(bf16x8*)(ldsB + (wc * 32 + j * 16) * 64 + lo);
#pragma unroll
    for (int i = 0; i < 4; ++i)
#pragma unroll
      for (int j = 0; j < 2; ++j)
        acc[i][j] = __builtin_amdgcn_mfma_f32_16x16x32_bf16(aF[i], bF[j], acc[i][j], 0, 0, 0);
    __syncthreads();
  }
#pragma unroll
  for (int i = 0; i < 4; ++i)
#pragma unroll
    for (int j = 0; j < 2; ++j)
#pragma unroll
      for (int r = 0; r < 4; ++r) {
        int eg = ebase + wr * 64 + i * 16 + (l >> 4) * 4 + r;
        int tg = tokbase + wc * 32 + j * 16 + (l & 15);
        outT[(size_t)eg * NTOK + tg] = (bf16)(acc[i][j][r] + bv[eg]);
      }
}

// ---------------------------------------------------------------------------
// Kernel 3: gathered head projection, natural output.
//   sel[tok][e] = sum_d head[b, head_idx[tok], d] * head_W[e][d] + head_b[e]
// A-operand = gathered head rows (rows tok, k=d), B-operand = head_W (cols e).
// Tile: 128 tok-rows x 64 e-cols, BK=32.
// ---------------------------------------------------------------------------
__global__ __launch_bounds__(256) void projB_k(const float* __restrict__ head,
                                               const int* __restrict__ hidx,
                                               const float* __restrict__ Wp,
                                               const float* __restrict__ bv,
                                               bf16* __restrict__ selO) {
  __shared__ char lds[12288];
  char* ldsA = lds;          // [128 tok][32 d]
  char* ldsB = lds + 8192;   // [64 e][32 d]
  const int tid = threadIdx.x, l = tid & 63, w = tid >> 6;
  const int tokbase = blockIdx.x * 128;
  const int ebase   = blockIdx.y * 64;
  const int wr = w & 1, wc = w >> 1;
  f32x4 acc[4][2] = {};
  const int arow = tid >> 1, ahalf = tid & 1;
  const int brow = tid >> 2, bgr = tid & 3;
  const int flat = tokbase + arow;
  const int bb = flat >> 11;                       // batch = flat / 2048
  const int hv = hidx[flat];                       // 0..2048
  const float* aS = head + ((size_t)bb * 2049 + hv) * 1024 + ahalf * 16;
  const float* bS = Wp + (size_t)(ebase + brow) * 1024 + bgr * 8;
  const int lo = (l & 15) * 64 + (l >> 4) * 16;
  for (int kb = 0; kb < 1024; kb += 32) {
    float4 a0 = *(const float4*)(aS + kb);
    float4 a1 = *(const float4*)(aS + kb + 4);
    float4 a2 = *(const float4*)(aS + kb + 8);
    float4 a3 = *(const float4*)(aS + kb + 12);
    float4 b0 = *(const float4*)(bS + kb);
    float4 b1 = *(const float4*)(bS + kb + 4);
    *(bf16x8*)(ldsA + arow * 64 + ahalf * 32)      = cvt8(a0, a1);
    *(bf16x8*)(ldsA + arow * 64 + ahalf * 32 + 16) = cvt8(a2, a3);
    *(bf16x8*)(ldsB + brow * 64 + bgr * 16)        = cvt8(b0, b1);
    __syncthreads();
    bf16x8 aF[4], bF[2];
#pragma unroll
    for (int i = 0; i < 4; ++i) aF[i] = *(bf16x8*)(ldsA + (wr * 64 + i * 16) * 64 + lo);
#pragma unroll
    for (int j = 0; j < 2; ++j) bF[j] = *(bf16x8*)(ldsB + (wc * 32 + j * 16) * 64 + lo);
#pragma unroll
    for (int i = 0; i < 4; ++i)
#pragma unroll
      for (int j = 0; j < 2; ++j)
        acc[i][j] = __builtin_amdgcn_mfma_f32_16x16x32_bf16(aF[i], bF[j], acc[i][j], 0, 0, 0);
    __syncthreads();
  }
#pragma unroll
  for (int i = 0; i < 4; ++i)
#pragma unroll
    for (int j = 0; j < 2; ++j)
#pragma unroll
      for (int r = 0; r < 4; ++r) {
        int tg = tokbase + wr * 64 + i * 16 + (l >> 4) * 4 + r;
        int eg = ebase + wc * 32 + j * 16 + (l & 15);
        selO[(size_t)tg * DLBL + eg] = (bf16)(acc[i][j][r] + bv[eg]);
      }
}

// ---------------------------------------------------------------------------
// Kernel 4: biaffine main GEMM + fused reduction.
//   H[d,tok] = sum_e W[n,d,e] * sel[tok,e]   (MFMA, K=e)
//   partial[dquad*2+wd][tok][n] = sum_{d in wave range} H[d,tok]*dep_t[d][tok]
// grid (32 tokTiles, 50 n, 4 dquads); block 256 = 4 waves (wd=w>>1, wt=w&1);
// wave tile 64d x 64tok = 4x4 frags of 16x16x32; BK=32.
// ---------------------------------------------------------------------------
__global__ __launch_bounds__(256) void biaff_k(const bf16* __restrict__ Wb,
                                               const bf16* __restrict__ sel,
                                               const bf16* __restrict__ depT,
                                               float* __restrict__ parts) {
  __shared__ char lds[16384];
  char* ldsW = lds;          // [128 d][32 e] bf16
  char* ldsS = lds + 8192;   // [128 tok][32 e] bf16
  const int tid = threadIdx.x, l = tid & 63, w = tid >> 6;
  const int tokbase = blockIdx.x * 128;
  const int n = blockIdx.y;
  const int dblk = blockIdx.z * 128;
  const int wd = w >> 1, wt = w & 1;
  f32x4 acc[4][4] = {};
  const int srow = tid >> 1, shalf = tid & 1;      // 128 rows, 2 thr/row, 32B each
  const bf16* wS = Wb  + ((size_t)(n * DLBL + dblk + srow)) * DLBL + shalf * 16;
  const bf16* sS = sel + (size_t)(tokbase + srow) * DLBL + shalf * 16;
  const int lo = (l & 15) * 64 + (l >> 4) * 16;
  for (int eb = 0; eb < 512; eb += 32) {
    bf16x8 w0 = *(const bf16x8*)(wS + eb);
    bf16x8 w1 = *(const bf16x8*)(wS + eb + 8);
    bf16x8 s0 = *(const bf16x8*)(sS + eb);
    bf16x8 s1 = *(const bf16x8*)(sS + eb + 8);
    *(bf16x8*)(ldsW + srow * 64 + shalf * 32)      = w0;
    *(bf16x8*)(ldsW + srow * 64 + shalf * 32 + 16) = w1;
    *(bf16x8*)(ldsS + srow * 64 + shalf * 32)      = s0;
    *(bf16x8*)(ldsS + srow * 64 + shalf * 32 + 16) = s1;
    __syncthreads();
    bf16x8 aF[4], bF[4];
#pragma unroll
    for (int i = 0; i < 4; ++i) aF[i] = *(bf16x8*)(ldsW + (wd * 64 + i * 16) * 64 + lo);
#pragma unroll
    for (int j = 0; j < 4; ++j) bF[j] = *(bf16x8*)(ldsS + (wt * 64 + j * 16) * 64 + lo);
#pragma unroll
    for (int i = 0; i < 4; ++i)
#pragma unroll
      for (int j = 0; j < 4; ++j)
        acc[i][j] = __builtin_amdgcn_mfma_f32_16x16x32_bf16(aF[i], bF[j], acc[i][j], 0, 0, 0);
    __syncthreads();
  }
  // Epilogue: multiply by dep_label^T and reduce over the wave's 64 d values.
  float p[4] = {0.f, 0.f, 0.f, 0.f};
#pragma unroll
  for (int j = 0; j < 4; ++j)
#pragma unroll
    for (int i = 0; i < 4; ++i)
#pragma unroll
      for (int r = 0; r < 4; ++r) {
        int dg = dblk + wd * 64 + i * 16 + (l >> 4) * 4 + r;
        int tg = tokbase + wt * 64 + j * 16 + (l & 15);
        p[j] += acc[i][j][r] * (float)depT[(size_t)dg * NTOK + tg];
      }
#pragma unroll
  for (int j = 0; j < 4; ++j) {
    p[j] += __shfl_xor(p[j], 16);
    p[j] += __shfl_xor(p[j], 32);
  }
  if (l < 16) {
#pragma unroll
    for (int j = 0; j < 4; ++j) {
      int tg = tokbase + wt * 64 + j * 16 + l;
      parts[(size_t)(blockIdx.z * 2 + wd) * 204800 + (size_t)tg * NLAB + n] = p[j];
    }
  }
}

// ---------------------------------------------------------------------------
// Kernel 5: sum the 8 d-partials + bias -> logits [4096][50] f32
// ---------------------------------------------------------------------------
__global__ __launch_bounds__(256) void fin_k(const float* __restrict__ parts,
                                             const float* __restrict__ bias,
                                             float* __restrict__ out) {
  int i = blockIdx.x * 256 + threadIdx.x;          // 800*256 = 204800 exact
  float v = 0.f;
#pragma unroll
  for (int q = 0; q < 8; ++q) v += parts[(size_t)q * 204800 + i];
  out[i] = v + bias[i % NLAB];
}

// ---------------------------------------------------------------------------
extern "C" void kernel_launch(void* const* d_in, const int* in_sizes, int n_in,
                              void* d_out, int out_size, void* d_ws, size_t ws_size,
                              hipStream_t stream) {
  const float* dep    = (const float*)d_in[0];
  const float* head   = (const float*)d_in[1];
  const int*   hidx   = (const int*)d_in[2];
  // d_in[3] = mask (unused by reference math)
  const float* dep_W  = (const float*)d_in[4];
  const float* dep_b  = (const float*)d_in[5];
  const float* head_W = (const float*)d_in[6];
  const float* head_b = (const float*)d_in[7];
  const float* W      = (const float*)d_in[8];
  const float* bias   = (const float*)d_in[9];
  float* out = (float*)d_out;

  char* ws = (char*)d_ws;
  // ws layout (bytes):
  //   Wb    : 50*512*512*2      = 26,214,400
  //   dep_t : 512*4096*2        =  4,194,304   (dep_label transposed, bf16)
  //   sel   : 4096*512*2        =  4,194,304   (gathered head_label, bf16)
  //   parts : 8*4096*50*4       =  6,553,600
  bf16*  Wb    = (bf16*)(ws);
  bf16*  depT  = (bf16*)(ws + 26214400);
  bf16*  selB  = (bf16*)(ws + 30408704);
  float* parts = (float*)(ws + 34603008);
  if (ws_size < (size_t)41156608) return;  // insufficient scratch: bail safely

  hipLaunchKernelGGL(convW_k, dim3(6400), dim3(256), 0, stream, W, Wb);
  hipLaunchKernelGGL(projA_k, dim3(64, 4), dim3(256), 0, stream, dep_W, dep, dep_b, depT);
  hipLaunchKernelGGL(projB_k, dim3(32, 8), dim3(256), 0, stream, head, hidx, head_W, head_b, selB);
  hipLaunchKernelGGL(biaff_k, dim3(32, 50, 4), dim3(256), 0, stream, Wb, selB, depT, parts);
  hipLaunchKernelGGL(fin_k, dim3(800), dim3(256), 0, stream, parts, bias, out);
}

// Round 2
// 245.691 us; speedup vs baseline: 1.0965x; 1.0965x over previous
//
#include <hip/hip_runtime.h>
#include <hip/hip_bf16.h>
#include <cstdint>

typedef __bf16 bf16;
typedef bf16 bf16x8 __attribute__((ext_vector_type(8)));
typedef float f32x4 __attribute__((ext_vector_type(4)));

#define NTOK 4096   // B*T
#define DLBL 512    // D_LABEL
#define NLAB 50

__device__ inline bf16x8 cvt8(float4 a, float4 b) {
  bf16x8 r;
  r[0] = (bf16)a.x; r[1] = (bf16)a.y; r[2] = (bf16)a.z; r[3] = (bf16)a.w;
  r[4] = (bf16)b.x; r[5] = (bf16)b.y; r[6] = (bf16)b.z; r[7] = (bf16)b.w;
  return r;
}

// async global->LDS, 16B per lane; LDS dest = wave-uniform base + lane*16
__device__ __forceinline__ void gl16(const bf16* g, void* l) {
  __builtin_amdgcn_global_load_lds(
      (const __attribute__((address_space(1))) void*)g,
      (__attribute__((address_space(3))) void*)l, 16, 0, 0);
}

// ---------------------------------------------------------------------------
// Kernel 1: convert biaffine W [50][512][512] f32 -> bf16 (same layout)
// ---------------------------------------------------------------------------
__global__ __launch_bounds__(256) void convW_k(const float* __restrict__ W,
                                               bf16* __restrict__ Wb) {
  int i = blockIdx.x * 256 + threadIdx.x;
  const float4* s = (const float4*)W + (size_t)i * 2;
  float4 a = s[0], b = s[1];
  *(bf16x8*)(Wb + (size_t)i * 8) = cvt8(a, b);
}

// ---------------------------------------------------------------------------
// Kernel 2: dep projection, TRANSPOSED output. LDS rows padded to 80B
// (stride-5 16B slots: frag reads conflict-free, writes 2-way=free).
// ---------------------------------------------------------------------------
__global__ __launch_bounds__(256) void projA_k(const float* __restrict__ Wp,
                                               const float* __restrict__ X,
                                               const float* __restrict__ bv,
                                               bf16* __restrict__ outT) {
  __shared__ char lds[15360];
  char* ldsA = lds;           // [128 e][32 d] bf16, row stride 80B
  char* ldsB = lds + 10240;   // [64 tok][32 d] bf16, row stride 80B
  const int tid = threadIdx.x, l = tid & 63, w = tid >> 6;
  const int tokbase = blockIdx.x * 64;
  const int ebase   = blockIdx.y * 128;
  const int wr = w & 1, wc = w >> 1;
  f32x4 acc[4][2] = {};
  const int arow = tid >> 1, ahalf = tid & 1;
  const int brow = tid >> 2, bgr = tid & 3;
  const float* aS = Wp + (size_t)(ebase + arow) * 1024 + ahalf * 16;
  const float* bS = X  + (size_t)(tokbase + brow) * 1024 + bgr * 8;
  const int lo = (l & 15) * 80 + (l >> 4) * 16;
  for (int kb = 0; kb < 1024; kb += 32) {
    float4 a0 = *(const float4*)(aS + kb);
    float4 a1 = *(const float4*)(aS + kb + 4);
    float4 a2 = *(const float4*)(aS + kb + 8);
    float4 a3 = *(const float4*)(aS + kb + 12);
    float4 b0 = *(const float4*)(bS + kb);
    float4 b1 = *(const float4*)(bS + kb + 4);
    *(bf16x8*)(ldsA + arow * 80 + ahalf * 32)      = cvt8(a0, a1);
    *(bf16x8*)(ldsA + arow * 80 + ahalf * 32 + 16) = cvt8(a2, a3);
    *(bf16x8*)(ldsB + brow * 80 + bgr * 16)        = cvt8(b0, b1);
    __syncthreads();
    bf16x8 aF[4], bF[2];
#pragma unroll
    for (int i = 0; i < 4; ++i) aF[i] = *(bf16x8*)(ldsA + (wr * 64 + i * 16) * 80 + lo);
#pragma unroll
    for (int j = 0; j < 2; ++j) bF[j] = *(bf16x8*)(ldsB + (wc * 32 + j * 16) * 80 + lo);
#pragma unroll
    for (int i = 0; i < 4; ++i)
#pragma unroll
      for (int j = 0; j < 2; ++j)
        acc[i][j] = __builtin_amdgcn_mfma_f32_16x16x32_bf16(aF[i], bF[j], acc[i][j], 0, 0, 0);
    __syncthreads();
  }
#pragma unroll
  for (int i = 0; i < 4; ++i)
#pragma unroll
    for (int j = 0; j < 2; ++j)
#pragma unroll
      for (int r = 0; r < 4; ++r) {
        int eg = ebase + wr * 64 + i * 16 + (l >> 4) * 4 + r;
        int tg = tokbase + wc * 32 + j * 16 + (l & 15);
        outT[(size_t)eg * NTOK + tg] = (bf16)(acc[i][j][r] + bv[eg]);
      }
}

// ---------------------------------------------------------------------------
// Kernel 3: gathered head projection, natural output. Same 80B-pad fix.
// ---------------------------------------------------------------------------
__global__ __launch_bounds__(256) void projB_k(const float* __restrict__ head,
                                               const int* __restrict__ hidx,
                                               const float* __restrict__ Wp,
                                               const float* __restrict__ bv,
                                               bf16* __restrict__ selO) {
  __shared__ char lds[15360];
  char* ldsA = lds;           // [128 tok][32 d], stride 80
  char* ldsB = lds + 10240;   // [64 e][32 d], stride 80
  const int tid = threadIdx.x, l = tid & 63, w = tid >> 6;
  const int tokbase = blockIdx.x * 128;
  const int ebase   = blockIdx.y * 64;
  const int wr = w & 1, wc = w >> 1;
  f32x4 acc[4][2] = {};
  const int arow = tid >> 1, ahalf = tid & 1;
  const int brow = tid >> 2, bgr = tid & 3;
  const int flat = tokbase + arow;
  const int bb = flat >> 11;
  const int hv = hidx[flat];
  const float* aS = head + ((size_t)bb * 2049 + hv) * 1024 + ahalf * 16;
  const float* bS = Wp + (size_t)(ebase + brow) * 1024 + bgr * 8;
  const int lo = (l & 15) * 80 + (l >> 4) * 16;
  for (int kb = 0; kb < 1024; kb += 32) {
    float4 a0 = *(const float4*)(aS + kb);
    float4 a1 = *(const float4*)(aS + kb + 4);
    float4 a2 = *(const float4*)(aS + kb + 8);
    float4 a3 = *(const float4*)(aS + kb + 12);
    float4 b0 = *(const float4*)(bS + kb);
    float4 b1 = *(const float4*)(bS + kb + 4);
    *(bf16x8*)(ldsA + arow * 80 + ahalf * 32)      = cvt8(a0, a1);
    *(bf16x8*)(ldsA + arow * 80 + ahalf * 32 + 16) = cvt8(a2, a3);
    *(bf16x8*)(ldsB + brow * 80 + bgr * 16)        = cvt8(b0, b1);
    __syncthreads();
    bf16x8 aF[4], bF[2];
#pragma unroll
    for (int i = 0; i < 4; ++i) aF[i] = *(bf16x8*)(ldsA + (wr * 64 + i * 16) * 80 + lo);
#pragma unroll
    for (int j = 0; j < 2; ++j) bF[j] = *(bf16x8*)(ldsB + (wc * 32 + j * 16) * 80 + lo);
#pragma unroll
    for (int i = 0; i < 4; ++i)
#pragma unroll
      for (int j = 0; j < 2; ++j)
        acc[i][j] = __builtin_amdgcn_mfma_f32_16x16x32_bf16(aF[i], bF[j], acc[i][j], 0, 0, 0);
    __syncthreads();
  }
#pragma unroll
  for (int i = 0; i < 4; ++i)
#pragma unroll
    for (int j = 0; j < 2; ++j)
#pragma unroll
      for (int r = 0; r < 4; ++r) {
        int tg = tokbase + wr * 64 + i * 16 + (l >> 4) * 4 + r;
        int eg = ebase + wc * 32 + j * 16 + (l & 15);
        selO[(size_t)tg * DLBL + eg] = (bf16)(acc[i][j][r] + bv[eg]);
      }
}

// ---------------------------------------------------------------------------
// Kernel 4 v2: biaffine main GEMM + fused reduction.
//   Block: 512 thr (8 waves), tile 128 d x 256 tok, BK=64 (8 K-steps).
//   Staging via global_load_lds width-16, XOR-swizzled SOURCE address so the
//   LDS image has byte ^= ((row&7)<<4); frag reads apply the same XOR ->
//   conflict-free reads AND writes (linear LDS dest as gload_lds requires).
//   Wave grid 2(d) x 4(tok); wave tile 64d x 64tok = 4x4 frags 16x16x32.
//   Grid: 1D 3200 with bijective XCD swizzle (3200 % 8 == 0) so blocks
//   sharing a W[n] panel co-reside on one XCD's L2.
// ---------------------------------------------------------------------------
__global__ __launch_bounds__(512, 4) void biaff_k(const bf16* __restrict__ Wb,
                                                  const bf16* __restrict__ sel,
                                                  const bf16* __restrict__ depT,
                                                  float* __restrict__ parts) {
  __shared__ char lds[49152];
  char* ldsA = lds;            // [128 d][64 e] bf16, 128B rows, swizzled image
  char* ldsB = lds + 16384;    // [256 t][64 e] bf16, 128B rows, swizzled image
  const int tid = threadIdx.x, l = tid & 63, w = tid >> 6;

  // XCD-aware decode: lin%8 = HW XCD; give each XCD a contiguous logical range.
  const int lin = blockIdx.x;
  const int sw  = (lin & 7) * 400 + (lin >> 3);
  const int bx  = sw & 15;          // tok tile (fastest -> same-n blocks adjacent)
  const int rem = sw >> 4;          // 0..199
  const int n   = rem % 50;
  const int dz  = rem / 50;         // 0..3 (128-d block)
  const int tokbase = bx * 256;
  const int dbase   = dz * 128;

  const int wd = w >> 2, wt = w & 3;         // wave tile: 64 d x 64 tok
  f32x4 acc[4][4] = {};

  // staging source chunk swizzle: lane l stages LDS (row', chunk l&7) where
  // row'&7 == l>>3; source chunk = (l&7) ^ (l>>3)  (8 bf16 elems per chunk)
  const int schunk = ((l & 7) ^ (l >> 3)) * 8;
  const bf16* aG = Wb  + ((size_t)(n * DLBL + dbase + w * 16 + (l >> 3))) * DLBL + schunk;
  const bf16* bG = sel + ((size_t)(tokbase + w * 32 + (l >> 3))) * DLBL + schunk;
  char* aL = ldsA + (w * 16) * 128;   // + lane*16 done by HW
  char* bL = ldsB + (w * 32) * 128;

  const int lq = l & 15, lh = l >> 4, l7 = l & 7;

  for (int eb = 0; eb < DLBL; eb += 64) {
    // ---- stage A (2 calls: 16 rows/wave) and B (4 calls: 32 rows/wave) ----
    gl16(aG + eb,                aL);
    gl16(aG + eb + 8 * DLBL,     aL + 8 * 128);
    gl16(bG + eb,                bL);
    gl16(bG + eb + 8 * DLBL,     bL + 8 * 128);
    gl16(bG + eb + 16 * DLBL,    bL + 16 * 128);
    gl16(bG + eb + 24 * DLBL,    bL + 24 * 128);
    __syncthreads();              // drains vmcnt -> tiles ready
#pragma unroll
    for (int ks = 0; ks < 2; ++ks) {
      const int kc = ks * 4 + lh;
      bf16x8 aF[4], bF[4];
#pragma unroll
      for (int i = 0; i < 4; ++i)
        aF[i] = *(bf16x8*)(ldsA + (wd * 64 + i * 16 + lq) * 128 + (kc ^ l7) * 16);
#pragma unroll
      for (int j = 0; j < 4; ++j)
        bF[j] = *(bf16x8*)(ldsB + (wt * 64 + j * 16 + lq) * 128 + (kc ^ l7) * 16);
#pragma unroll
      for (int i = 0; i < 4; ++i)
#pragma unroll
        for (int j = 0; j < 4; ++j)
          acc[i][j] = __builtin_amdgcn_mfma_f32_16x16x32_bf16(aF[i], bF[j], acc[i][j], 0, 0, 0);
    }
    __syncthreads();              // all reads done before next stage overwrites
  }

  // ---- epilogue: H[d,t] * depT[d,t], reduce over the wave's 64 d ----
  float p[4] = {0.f, 0.f, 0.f, 0.f};
#pragma unroll
  for (int j = 0; j < 4; ++j) {
    const int tg = tokbase + wt * 64 + j * 16 + lq;
#pragma unroll
    for (int i = 0; i < 4; ++i)
#pragma unroll
      for (int r = 0; r < 4; ++r) {
        int dg = dbase + wd * 64 + i * 16 + lh * 4 + r;
        p[j] += acc[i][j][r] * (float)depT[(size_t)dg * NTOK + tg];
      }
  }
#pragma unroll
  for (int j = 0; j < 4; ++j) {
    p[j] += __shfl_xor(p[j], 16);
    p[j] += __shfl_xor(p[j], 32);
  }
  if (l < 16) {
#pragma unroll
    for (int j = 0; j < 4; ++j) {
      int tg = tokbase + wt * 64 + j * 16 + l;
      parts[(size_t)(dz * 2 + wd) * 204800 + (size_t)tg * NLAB + n] = p[j];
    }
  }
}

// ---------------------------------------------------------------------------
// Kernel 5: sum the 8 d-partials + bias -> logits [4096][50] f32
// ---------------------------------------------------------------------------
__global__ __launch_bounds__(256) void fin_k(const float* __restrict__ parts,
                                             const float* __restrict__ bias,
                                             float* __restrict__ out) {
  int i = blockIdx.x * 256 + threadIdx.x;
  float v = 0.f;
#pragma unroll
  for (int q = 0; q < 8; ++q) v += parts[(size_t)q * 204800 + i];
  out[i] = v + bias[i % NLAB];
}

// ---------------------------------------------------------------------------
extern "C" void kernel_launch(void* const* d_in, const int* in_sizes, int n_in,
                              void* d_out, int out_size, void* d_ws, size_t ws_size,
                              hipStream_t stream) {
  const float* dep    = (const float*)d_in[0];
  const float* head   = (const float*)d_in[1];
  const int*   hidx   = (const int*)d_in[2];
  const float* dep_W  = (const float*)d_in[4];
  const float* dep_b  = (const float*)d_in[5];
  const float* head_W = (const float*)d_in[6];
  const float* head_b = (const float*)d_in[7];
  const float* W      = (const float*)d_in[8];
  const float* bias   = (const float*)d_in[9];
  float* out = (float*)d_out;

  char* ws = (char*)d_ws;
  bf16*  Wb    = (bf16*)(ws);
  bf16*  depT  = (bf16*)(ws + 26214400);
  bf16*  selB  = (bf16*)(ws + 30408704);
  float* parts = (float*)(ws + 34603008);
  if (ws_size < (size_t)41156608) return;

  hipLaunchKernelGGL(convW_k, dim3(6400), dim3(256), 0, stream, W, Wb);
  hipLaunchKernelGGL(projA_k, dim3(64, 4), dim3(256), 0, stream, dep_W, dep, dep_b, depT);
  hipLaunchKernelGGL(projB_k, dim3(32, 8), dim3(256), 0, stream, head, hidx, head_W, head_b, selB);
  hipLaunchKernelGGL(biaff_k, dim3(3200), dim3(512), 0, stream, Wb, selB, depT, parts);
  hipLaunchKernelGGL(fin_k, dim3(800), dim3(256), 0, stream, parts, bias, out);
}

// Round 3
// 208.359 us; speedup vs baseline: 1.2930x; 1.1792x over previous
//
#include <hip/hip_runtime.h>
#include <hip/hip_bf16.h>
#include <cstdint>

typedef __bf16 bf16;
typedef bf16 bf16x8 __attribute__((ext_vector_type(8)));
typedef float f32x4 __attribute__((ext_vector_type(4)));

#define NTOK 4096   // B*T
#define DLBL 512    // D_LABEL
#define NLAB 50

__device__ inline bf16x8 cvt8(float4 a, float4 b) {
  bf16x8 r;
  r[0] = (bf16)a.x; r[1] = (bf16)a.y; r[2] = (bf16)a.z; r[3] = (bf16)a.w;
  r[4] = (bf16)b.x; r[5] = (bf16)b.y; r[6] = (bf16)b.z; r[7] = (bf16)b.w;
  return r;
}

// async global->LDS, 16B per lane; LDS dest = wave-uniform base + lane*16
__device__ __forceinline__ void gl16(const bf16* g, void* l) {
  __builtin_amdgcn_global_load_lds(
      (const __attribute__((address_space(1))) void*)g,
      (__attribute__((address_space(3))) void*)l, 16, 0, 0);
}

// ---------------------------------------------------------------------------
// Kernel 1: convert biaffine W [50][512][512] f32 -> bf16 (same layout)
// ---------------------------------------------------------------------------
__global__ __launch_bounds__(256) void convW_k(const float* __restrict__ W,
                                               bf16* __restrict__ Wb) {
  int i = blockIdx.x * 256 + threadIdx.x;
  const float4* s = (const float4*)W + (size_t)i * 2;
  float4 a = s[0], b = s[1];
  *(bf16x8*)(Wb + (size_t)i * 8) = cvt8(a, b);
}

// ---------------------------------------------------------------------------
// Kernel 2: dep projection, TRANSPOSED output. LDS rows padded to 80B.
// Grid: (x = 4 e-tiles fastest, y = 64 tok-tiles) -> adjacent blocks share
// the 256KB dep tok-tile in L2.
// ---------------------------------------------------------------------------
__global__ __launch_bounds__(256) void projA_k(const float* __restrict__ Wp,
                                               const float* __restrict__ X,
                                               const float* __restrict__ bv,
                                               bf16* __restrict__ outT) {
  __shared__ char lds[15360];
  char* ldsA = lds;           // [128 e][32 d] bf16, row stride 80B
  char* ldsB = lds + 10240;   // [64 tok][32 d] bf16, row stride 80B
  const int tid = threadIdx.x, l = tid & 63, w = tid >> 6;
  const int tokbase = blockIdx.y * 64;
  const int ebase   = blockIdx.x * 128;
  const int wr = w & 1, wc = w >> 1;
  f32x4 acc[4][2] = {};
  const int arow = tid >> 1, ahalf = tid & 1;
  const int brow = tid >> 2, bgr = tid & 3;
  const float* aS = Wp + (size_t)(ebase + arow) * 1024 + ahalf * 16;
  const float* bS = X  + (size_t)(tokbase + brow) * 1024 + bgr * 8;
  const int lo = (l & 15) * 80 + (l >> 4) * 16;
  for (int kb = 0; kb < 1024; kb += 32) {
    float4 a0 = *(const float4*)(aS + kb);
    float4 a1 = *(const float4*)(aS + kb + 4);
    float4 a2 = *(const float4*)(aS + kb + 8);
    float4 a3 = *(const float4*)(aS + kb + 12);
    float4 b0 = *(const float4*)(bS + kb);
    float4 b1 = *(const float4*)(bS + kb + 4);
    *(bf16x8*)(ldsA + arow * 80 + ahalf * 32)      = cvt8(a0, a1);
    *(bf16x8*)(ldsA + arow * 80 + ahalf * 32 + 16) = cvt8(a2, a3);
    *(bf16x8*)(ldsB + brow * 80 + bgr * 16)        = cvt8(b0, b1);
    __syncthreads();
    bf16x8 aF[4], bF[2];
#pragma unroll
    for (int i = 0; i < 4; ++i) aF[i] = *(bf16x8*)(ldsA + (wr * 64 + i * 16) * 80 + lo);
#pragma unroll
    for (int j = 0; j < 2; ++j) bF[j] = *(bf16x8*)(ldsB + (wc * 32 + j * 16) * 80 + lo);
#pragma unroll
    for (int i = 0; i < 4; ++i)
#pragma unroll
      for (int j = 0; j < 2; ++j)
        acc[i][j] = __builtin_amdgcn_mfma_f32_16x16x32_bf16(aF[i], bF[j], acc[i][j], 0, 0, 0);
    __syncthreads();
  }
#pragma unroll
  for (int i = 0; i < 4; ++i)
#pragma unroll
    for (int j = 0; j < 2; ++j)
#pragma unroll
      for (int r = 0; r < 4; ++r) {
        int eg = ebase + wr * 64 + i * 16 + (l >> 4) * 4 + r;
        int tg = tokbase + wc * 32 + j * 16 + (l & 15);
        outT[(size_t)eg * NTOK + tg] = (bf16)(acc[i][j][r] + bv[eg]);
      }
}

// ---------------------------------------------------------------------------
// Kernel 3: gathered head projection, natural output. Same 80B-pad fix.
// Grid: (x = 8 e-tiles fastest, y = 32 tok-tiles) -> gathered head rows shared.
// ---------------------------------------------------------------------------
__global__ __launch_bounds__(256) void projB_k(const float* __restrict__ head,
                                               const int* __restrict__ hidx,
                                               const float* __restrict__ Wp,
                                               const float* __restrict__ bv,
                                               bf16* __restrict__ selO) {
  __shared__ char lds[15360];
  char* ldsA = lds;           // [128 tok][32 d], stride 80
  char* ldsB = lds + 10240;   // [64 e][32 d], stride 80
  const int tid = threadIdx.x, l = tid & 63, w = tid >> 6;
  const int tokbase = blockIdx.y * 128;
  const int ebase   = blockIdx.x * 64;
  const int wr = w & 1, wc = w >> 1;
  f32x4 acc[4][2] = {};
  const int arow = tid >> 1, ahalf = tid & 1;
  const int brow = tid >> 2, bgr = tid & 3;
  const int flat = tokbase + arow;
  const int bb = flat >> 11;
  const int hv = hidx[flat];
  const float* aS = head + ((size_t)bb * 2049 + hv) * 1024 + ahalf * 16;
  const float* bS = Wp + (size_t)(ebase + brow) * 1024 + bgr * 8;
  const int lo = (l & 15) * 80 + (l >> 4) * 16;
  for (int kb = 0; kb < 1024; kb += 32) {
    float4 a0 = *(const float4*)(aS + kb);
    float4 a1 = *(const float4*)(aS + kb + 4);
    float4 a2 = *(const float4*)(aS + kb + 8);
    float4 a3 = *(const float4*)(aS + kb + 12);
    float4 b0 = *(const float4*)(bS + kb);
    float4 b1 = *(const float4*)(bS + kb + 4);
    *(bf16x8*)(ldsA + arow * 80 + ahalf * 32)      = cvt8(a0, a1);
    *(bf16x8*)(ldsA + arow * 80 + ahalf * 32 + 16) = cvt8(a2, a3);
    *(bf16x8*)(ldsB + brow * 80 + bgr * 16)        = cvt8(b0, b1);
    __syncthreads();
    bf16x8 aF[4], bF[2];
#pragma unroll
    for (int i = 0; i < 4; ++i) aF[i] = *(bf16x8*)(ldsA + (wr * 64 + i * 16) * 80 + lo);
#pragma unroll
    for (int j = 0; j < 2; ++j) bF[j] = *(bf16x8*)(ldsB + (wc * 32 + j * 16) * 80 + lo);
#pragma unroll
    for (int i = 0; i < 4; ++i)
#pragma unroll
      for (int j = 0; j < 2; ++j)
        acc[i][j] = __builtin_amdgcn_mfma_f32_16x16x32_bf16(aF[i], bF[j], acc[i][j], 0, 0, 0);
    __syncthreads();
  }
#pragma unroll
  for (int i = 0; i < 4; ++i)
#pragma unroll
    for (int j = 0; j < 2; ++j)
#pragma unroll
      for (int r = 0; r < 4; ++r) {
        int tg = tokbase + wr * 64 + i * 16 + (l >> 4) * 4 + r;
        int eg = ebase + wc * 32 + j * 16 + (l & 15);
        selO[(size_t)tg * DLBL + eg] = (bf16)(acc[i][j][r] + bv[eg]);
      }
}

// ---------------------------------------------------------------------------
// Kernel 4 v3: biaffine GEMM + fused reduction, double-buffered counted-vmcnt
// pipeline (T3+T4) + setprio (T5).
//   Block: 512 thr (8 waves), tile 128 d x 256 tok, BK=64 (8 K-steps).
//   LDS: 2 buffers x (A 16KB + B 32KB) = 96KB -> 1 block/CU (m201 regime).
//   Per K-step: issue next-tile stage (6 gl16) -> vmcnt(6) -> barrier ->
//   ds_read+MFMA (setprio-wrapped) -> barrier. Loads in flight across
//   barriers; vmcnt never drained to 0 in the main loop.
//   XCD swizzle: n-fastest within an XCD so the XCD's 25 W panels (3.2MB)
//   stay L2-resident and sel/depT tiles are reused 25x consecutively.
// ---------------------------------------------------------------------------
__global__ __launch_bounds__(512, 2) void biaff_k(const bf16* __restrict__ Wb,
                                                  const bf16* __restrict__ sel,
                                                  const bf16* __restrict__ depT,
                                                  float* __restrict__ parts) {
  __shared__ char lds[98304];
  const int tid = threadIdx.x, l = tid & 63, w = tid >> 6;

  // bijective XCD-aware decode: 3200 = 8 xcd * (16 tok * 25 rem), n fastest
  const int lin = blockIdx.x;
  const int xcd = lin & 7, idx = lin >> 3;   // idx 0..399
  const int sub = idx % 25;                  // fast: (n,dz) within xcd slice
  const int bx  = idx / 25;                  // slow: tok tile 0..15
  const int rem = xcd * 25 + sub;            // 0..199, globally unique
  const int n   = rem % 50;
  const int dz  = rem / 50;
  const int tokbase = bx * 256;
  const int dbase   = dz * 128;

  const int wd = w >> 2, wt = w & 3;         // wave tile: 64 d x 64 tok
  f32x4 acc[4][4] = {};

  // staging: lane l covers LDS (row w*R + l>>3, chunk l&7); source chunk
  // pre-swizzled by ^(l>>3) so the LDS image carries byte ^= ((row&7)<<4)
  const int schunk = ((l & 7) ^ (l >> 3)) * 8;
  const bf16* aG = Wb  + ((size_t)(n * DLBL + dbase + w * 16 + (l >> 3))) * DLBL + schunk;
  const bf16* bG = sel + ((size_t)(tokbase + w * 32 + (l >> 3))) * DLBL + schunk;
  const int aOff = (w * 16) * 128;
  const int bOff = 16384 + (w * 32) * 128;

  const int lq = l & 15, lh = l >> 4, l7 = l & 7;

#define STAGE(buf, eb) do { \
    char* aL = lds + (buf) * 49152 + aOff; \
    char* bL = lds + (buf) * 49152 + bOff; \
    gl16(aG + (eb),             aL); \
    gl16(aG + (eb) + 8 * DLBL,  aL + 8 * 128); \
    gl16(bG + (eb),             bL); \
    gl16(bG + (eb) + 8 * DLBL,  bL + 8 * 128); \
    gl16(bG + (eb) + 16 * DLBL, bL + 16 * 128); \
    gl16(bG + (eb) + 24 * DLBL, bL + 24 * 128); \
  } while (0)

  STAGE(0, 0);
  for (int t = 0; t < 8; ++t) {
    const int cur = t & 1;
    if (t < 7) {
      STAGE(cur ^ 1, (t + 1) * 64);
      asm volatile("s_waitcnt vmcnt(6)" ::: "memory");  // current tile's 6 done
    } else {
      asm volatile("s_waitcnt vmcnt(0)" ::: "memory");
    }
    __builtin_amdgcn_s_barrier();       // whole current tile visible
    const char* cA = lds + cur * 49152;
    const char* cB = cA + 16384;
    __builtin_amdgcn_s_setprio(1);
#pragma unroll
    for (int ks = 0; ks < 2; ++ks) {
      const int kc = ks * 4 + lh;
      bf16x8 aF[4], bF[4];
#pragma unroll
      for (int i = 0; i < 4; ++i)
        aF[i] = *(const bf16x8*)(cA + (wd * 64 + i * 16 + lq) * 128 + (kc ^ l7) * 16);
#pragma unroll
      for (int j = 0; j < 4; ++j)
        bF[j] = *(const bf16x8*)(cB + (wt * 64 + j * 16 + lq) * 128 + (kc ^ l7) * 16);
#pragma unroll
      for (int i = 0; i < 4; ++i)
#pragma unroll
        for (int j = 0; j < 4; ++j)
          acc[i][j] = __builtin_amdgcn_mfma_f32_16x16x32_bf16(aF[i], bF[j], acc[i][j], 0, 0, 0);
    }
    __builtin_amdgcn_s_setprio(0);
    __builtin_amdgcn_s_barrier();       // all reads of cur done before reuse
  }
#undef STAGE

  // ---- epilogue: H[d,t] * depT[d,t], reduce over the wave's 64 d ----
  float p[4] = {0.f, 0.f, 0.f, 0.f};
#pragma unroll
  for (int j = 0; j < 4; ++j) {
    const int tg = tokbase + wt * 64 + j * 16 + lq;
#pragma unroll
    for (int i = 0; i < 4; ++i)
#pragma unroll
      for (int r = 0; r < 4; ++r) {
        int dg = dbase + wd * 64 + i * 16 + lh * 4 + r;
        p[j] += acc[i][j][r] * (float)depT[(size_t)dg * NTOK + tg];
      }
  }
#pragma unroll
  for (int j = 0; j < 4; ++j) {
    p[j] += __shfl_xor(p[j], 16);
    p[j] += __shfl_xor(p[j], 32);
  }
  if (l < 16) {
#pragma unroll
    for (int j = 0; j < 4; ++j) {
      int tg = tokbase + wt * 64 + j * 16 + l;
      parts[(size_t)(dz * 2 + wd) * 204800 + (size_t)tg * NLAB + n] = p[j];
    }
  }
}

// ---------------------------------------------------------------------------
// Kernel 5: sum the 8 d-partials + bias -> logits [4096][50] f32
// ---------------------------------------------------------------------------
__global__ __launch_bounds__(256) void fin_k(const float* __restrict__ parts,
                                             const float* __restrict__ bias,
                                             float* __restrict__ out) {
  int i = blockIdx.x * 256 + threadIdx.x;
  float v = 0.f;
#pragma unroll
  for (int q = 0; q < 8; ++q) v += parts[(size_t)q * 204800 + i];
  out[i] = v + bias[i % NLAB];
}

// ---------------------------------------------------------------------------
extern "C" void kernel_launch(void* const* d_in, const int* in_sizes, int n_in,
                              void* d_out, int out_size, void* d_ws, size_t ws_size,
                              hipStream_t stream) {
  const float* dep    = (const float*)d_in[0];
  const float* head   = (const float*)d_in[1];
  const int*   hidx   = (const int*)d_in[2];
  const float* dep_W  = (const float*)d_in[4];
  const float* dep_b  = (const float*)d_in[5];
  const float* head_W = (const float*)d_in[6];
  const float* head_b = (const float*)d_in[7];
  const float* W      = (const float*)d_in[8];
  const float* bias   = (const float*)d_in[9];
  float* out = (float*)d_out;

  char* ws = (char*)d_ws;
  bf16*  Wb    = (bf16*)(ws);
  bf16*  depT  = (bf16*)(ws + 26214400);
  bf16*  selB  = (bf16*)(ws + 30408704);
  float* parts = (float*)(ws + 34603008);
  if (ws_size < (size_t)41156608) return;

  hipLaunchKernelGGL(convW_k, dim3(6400), dim3(256), 0, stream, W, Wb);
  hipLaunchKernelGGL(projA_k, dim3(4, 64), dim3(256), 0, stream, dep_W, dep, dep_b, depT);
  hipLaunchKernelGGL(projB_k, dim3(8, 32), dim3(256), 0, stream, head, hidx, head_W, head_b, selB);
  hipLaunchKernelGGL(biaff_k, dim3(3200), dim3(512), 0, stream, Wb, selB, depT, parts);
  hipLaunchKernelGGL(fin_k, dim3(800), dim3(256), 0, stream, parts, bias, out);
}